// Round 18
// baseline (164.168 us; speedup 1.0000x reference)
//
#include <hip/hip_runtime.h>
#include <hip/hip_bf16.h>
#include <cstdint>

constexpr int Bsz = 2, Seq = 2048, Dim = 1024, NH = 16, HDim = 64;
constexpr int Mtok = Bsz * Seq;           // 4096
constexpr int NQKV = 3 * Dim;             // 3072
constexpr float QSCALE = 0.125f * 1.4426950408889634f;  // 1/sqrt(64) * log2(e)

typedef __attribute__((ext_vector_type(4))) float f32x4;
typedef __attribute__((ext_vector_type(16))) float f32x16;
typedef __attribute__((ext_vector_type(8))) short bf16x8;

#if __has_builtin(__builtin_amdgcn_exp2f)
#define EXP2(x) __builtin_amdgcn_exp2f(x)
#else
#define EXP2(x) exp2f(x)
#endif

__device__ __forceinline__ ushort f2bf(float f) {
    union { float f; uint32_t u; } v; v.f = f;
    uint32_t u = v.u;
    uint32_t r = (u + 0x7fffu + ((u >> 16) & 1u)) >> 16;
    return (ushort)r;
}

__device__ __forceinline__ uint cvt_pk_bf16(float lo, float hi) {
    uint r;
    asm("v_cvt_pk_bf16_f32 %0, %1, %2" : "=v"(r) : "v"(lo), "v"(hi));
    return r;
}

__device__ __forceinline__ void gll16(const ushort* g, ushort* l) {
    __builtin_amdgcn_global_load_lds(
        (const __attribute__((address_space(1))) void*)g,
        (__attribute__((address_space(3))) void*)l, 16, 0, 0);
}

// ---------------- fused prep: X->bf16 | 4x W transpose | bias concat ----------------
__global__ __launch_bounds__(256) void prep(const float* __restrict__ X,
                                            const float* __restrict__ Wq, const float* __restrict__ Wk,
                                            const float* __restrict__ Wv, const float* __restrict__ Wo,
                                            const float* __restrict__ bq, const float* __restrict__ bk,
                                            const float* __restrict__ bv,
                                            ushort* __restrict__ Xb, ushort* __restrict__ Wtqkv,
                                            ushort* __restrict__ Wto, float* __restrict__ bqkv) {
    __shared__ float tile[32][33];
    const int bid = blockIdx.x, tid = threadIdx.x;
    if (bid < 1024) {
        int i = bid * 256 + tid;
        const float4* p = (const float4*)X + (size_t)i * 4;
        float4 a = p[0], b = p[1], c2 = p[2], d = p[3];
        uint4 o0, o1;
        o0.x = (uint)f2bf(a.x) | ((uint)f2bf(a.y) << 16);
        o0.y = (uint)f2bf(a.z) | ((uint)f2bf(a.w) << 16);
        o0.z = (uint)f2bf(b.x) | ((uint)f2bf(b.y) << 16);
        o0.w = (uint)f2bf(b.z) | ((uint)f2bf(b.w) << 16);
        o1.x = (uint)f2bf(c2.x) | ((uint)f2bf(c2.y) << 16);
        o1.y = (uint)f2bf(c2.z) | ((uint)f2bf(c2.w) << 16);
        o1.z = (uint)f2bf(d.x) | ((uint)f2bf(d.y) << 16);
        o1.w = (uint)f2bf(d.z) | ((uint)f2bf(d.w) << 16);
        uint4* dst = (uint4*)Xb + (size_t)i * 2;
        dst[0] = o0;
        dst[1] = o1;
    } else if (bid < 5120) {
        int zb = bid - 1024;
        int z = zb >> 10, r2 = zb & 1023;
        int bx = (r2 & 31) * 32, by = (r2 >> 5) * 32;
        const float* src = (z == 0) ? Wq : (z == 1) ? Wk : (z == 2) ? Wv : Wo;
        ushort* dst = (z == 3) ? Wto : Wtqkv + (size_t)z * 1024 * 1024;
        float scale = (z == 0) ? QSCALE : 1.f;
        int tx = tid & 31, ty = tid >> 5;   // 32 x 8
#pragma unroll
        for (int j = 0; j < 32; j += 8)
            tile[ty + j][tx] = src[(size_t)(by + ty + j) * Dim + bx + tx];
        __syncthreads();
#pragma unroll
        for (int j = 0; j < 32; j += 8) {
            int n = bx + ty + j;
            dst[(size_t)n * Dim + by + tx] = f2bf(tile[tx][ty + j] * scale);
        }
    } else {
        int i = (bid - 5120) * 256 + tid;
        float v = (i < 1024) ? bq[i] * QSCALE : (i < 2048 ? bk[i - 1024] : bv[i - 2048]);
        bqkv[i] = v;
    }
}

// ---------------- QKV GEMM: 256x256 tile, BK=64, 8 waves, counted-vmcnt phase schedule ----------------
// XCD-chunked bijective swizzle (192 blocks, 24/XCD).
__global__ __launch_bounds__(512, 2) void gemm_qkv(const ushort* __restrict__ A,
                                                   const ushort* __restrict__ Bt,
                                                   const float* __restrict__ bias,
                                                   ushort* __restrict__ Qp,
                                                   ushort* __restrict__ Kp,
                                                   ushort* __restrict__ Vp) {
    __shared__ ushort Al[2][2][8192];
    __shared__ ushort Bl[2][2][8192];
    const int tid = threadIdx.x;
    const int lane = tid & 63, wid = tid >> 6;
    const int wm = wid >> 2, wn = wid & 3;
    const int g = lane >> 4, r16 = lane & 15;
    const int sw = r16 & 7;
    const int lin = blockIdx.x + blockIdx.y * 16;
    const int swz = (lin & 7) * 24 + (lin >> 3);
    const int by = swz >> 4;
    const int bm = (swz & 15) * 256, bn = by * 256;
    const int srow = tid >> 3;
    const int gch = (tid & 7) ^ (srow & 7);
    const int wofs = wid * 512;

    const ushort* gAb = A  + (size_t)(bm + srow) * 1024 + gch * 8;
    const ushort* gBb = Bt + (size_t)(bn + srow) * 1024 + gch * 8;

#define STAGE_A(buf, h, t) do {                                          \
        const ushort* s_ = gAb + (size_t)(h) * 131072 + (t) * 64;        \
        gll16(s_,         &Al[buf][h][wofs]);                            \
        gll16(s_ + 65536, &Al[buf][h][4096 + wofs]);                     \
    } while (0)
#define STAGE_B(buf, h, t) do {                                          \
        const ushort* s_ = gBb + (size_t)(h) * 131072 + (t) * 64;        \
        gll16(s_,         &Bl[buf][h][wofs]);                            \
        gll16(s_ + 65536, &Bl[buf][h][4096 + wofs]);                     \
    } while (0)
#define LDA(buf, mi, ks) (*(const bf16x8*)&Al[buf][wm][((mi)*16 + r16) * 64 + ((((ks)*4 + g) ^ sw) * 8)])
#define LDB(buf, ni, ks) (*(const bf16x8*)&Bl[buf][wn >> 1][((wn & 1) * 64 + (ni)*16 + r16) * 64 + ((((ks)*4 + g) ^ sw) * 8)])

    f32x4 acc[8][4] = {};
    bf16x8 a0[4][2], a1[4][2], bA[2][2], bB[2][2];

    STAGE_A(0, 0, 0); STAGE_A(0, 1, 0); STAGE_B(0, 0, 0); STAGE_B(0, 1, 0);
    STAGE_A(1, 0, 1); STAGE_A(1, 1, 1); STAGE_B(1, 0, 1); STAGE_B(1, 1, 1);
    asm volatile("s_waitcnt vmcnt(8)" ::: "memory");
    __builtin_amdgcn_s_barrier();
    __builtin_amdgcn_sched_barrier(0);

#pragma unroll 2
    for (int t = 0; t < 16; ++t) {
        const int buf = t & 1;
#pragma unroll
        for (int mi = 0; mi < 4; mi++) { a0[mi][0] = LDA(buf, mi, 0); a0[mi][1] = LDA(buf, mi, 1); }
#pragma unroll
        for (int ni = 0; ni < 2; ni++) { bA[ni][0] = LDB(buf, ni, 0); bA[ni][1] = LDB(buf, ni, 1); }
        __builtin_amdgcn_s_setprio(1);
#pragma unroll
        for (int mi = 0; mi < 4; mi++)
#pragma unroll
            for (int ni = 0; ni < 2; ni++)
#pragma unroll
                for (int ks = 0; ks < 2; ks++)
                    acc[mi][ni] = __builtin_amdgcn_mfma_f32_16x16x32_bf16(a0[mi][ks], bA[ni][ks], acc[mi][ni], 0, 0, 0);
        __builtin_amdgcn_s_setprio(0);
#pragma unroll
        for (int ni = 0; ni < 2; ni++) { bB[ni][0] = LDB(buf, 2 + ni, 0); bB[ni][1] = LDB(buf, 2 + ni, 1); }
        __builtin_amdgcn_s_setprio(1);
#pragma unroll
        for (int mi = 0; mi < 4; mi++)
#pragma unroll
            for (int ni = 0; ni < 2; ni++)
#pragma unroll
                for (int ks = 0; ks < 2; ks++)
                    acc[mi][2 + ni] = __builtin_amdgcn_mfma_f32_16x16x32_bf16(a0[mi][ks], bB[ni][ks], acc[mi][2 + ni], 0, 0, 0);
        __builtin_amdgcn_s_setprio(0);
        __builtin_amdgcn_s_barrier();
        __builtin_amdgcn_sched_barrier(0);
#pragma unroll
        for (int mi = 0; mi < 4; mi++) { a1[mi][0] = LDA(buf, 4 + mi, 0); a1[mi][1] = LDA(buf, 4 + mi, 1); }
        if (t + 2 < 16) { STAGE_B(buf, 0, t + 2); STAGE_B(buf, 1, t + 2); }
        __builtin_amdgcn_s_setprio(1);
#pragma unroll
        for (int mi = 0; mi < 4; mi++)
#pragma unroll
            for (int ni = 0; ni < 2; ni++)
#pragma unroll
                for (int ks = 0; ks < 2; ks++)
                    acc[4 + mi][2 + ni] = __builtin_amdgcn_mfma_f32_16x16x32_bf16(a1[mi][ks], bB[ni][ks], acc[4 + mi][2 + ni], 0, 0, 0);
        __builtin_amdgcn_s_setprio(0);
        __builtin_amdgcn_s_barrier();
        __builtin_amdgcn_sched_barrier(0);
        if (t + 2 < 16) { STAGE_A(buf, 0, t + 2); STAGE_A(buf, 1, t + 2); }
        __builtin_amdgcn_s_setprio(1);
#pragma unroll
        for (int mi = 0; mi < 4; mi++)
#pragma unroll
            for (int ni = 0; ni < 2; ni++)
#pragma unroll
                for (int ks = 0; ks < 2; ks++)
                    acc[4 + mi][ni] = __builtin_amdgcn_mfma_f32_16x16x32_bf16(a1[mi][ks], bA[ni][ks], acc[4 + mi][ni], 0, 0, 0);
        __builtin_amdgcn_s_setprio(0);
        if (t + 2 < 16) asm volatile("s_waitcnt vmcnt(8)" ::: "memory");
        else            asm volatile("s_waitcnt vmcnt(0)" ::: "memory");
        __builtin_amdgcn_s_barrier();
        __builtin_amdgcn_sched_barrier(0);
    }
#undef STAGE_A
#undef STAGE_B
#undef LDA
#undef LDB

#pragma unroll
    for (int ni = 0; ni < 4; ni++) {
        const int col = bn + wn * 64 + ni * 16 + r16;
        const float bv = bias[col];
        if (by < 4) {
#pragma unroll
            for (int mi = 0; mi < 8; mi++) {
                int row0 = bm + wm * 128 + mi * 16 + g * 4;
                f32x4 c = acc[mi][ni];
#pragma unroll
                for (int i = 0; i < 4; i++)
                    Qp[(size_t)(row0 + i) * 1024 + col] = f2bf(c[i] + bv);
            }
        } else if (by < 8) {
            int h = ((bn - 1024) >> 6) + wn;
            int d = ni * 16 + r16;
#pragma unroll
            for (int mi = 0; mi < 8; mi++) {
                int row0 = bm + wm * 128 + mi * 16 + g * 4;
                f32x4 c = acc[mi][ni];
#pragma unroll
                for (int i = 0; i < 4; i++) {
                    int row = row0 + i;
                    int b = row >> 11, s = row & 2047;
                    size_t idx = ((size_t)(b * 16 + h) * 2048 + s) * 64
                               + (((d >> 3) ^ (s & 7)) << 3) + (d & 7);
                    Kp[idx] = f2bf(c[i] + bv);
                }
            }
        } else {
            int h = ((bn - 2048) >> 6) + wn;
            int dv = ni * 16 + r16;
#pragma unroll
            for (int mi = 0; mi < 8; mi++) {
                int row0 = bm + wm * 128 + mi * 16 + g * 4;
                f32x4 c = acc[mi][ni];
                int b = row0 >> 11, s = row0 & 2047;
                int s0 = s & ~63, si = s & 63;
                uint2 pk;
                pk.x = cvt_pk_bf16(c[0] + bv, c[1] + bv);
                pk.y = cvt_pk_bf16(c[2] + bv, c[3] + bv);
                size_t idx = ((size_t)(b * 16 + h) * 2048 + s0) * 64 + dv * 64
                           + (((si >> 3) ^ (dv & 7)) << 3) + (si & 7);
                *(uint2*)(Vp + idx) = pk;
            }
        }
    }
}

// ---------------- out-proj GEMM (XCD swizzle: 256 blocks, 32/XCD) ----------------
__global__ __launch_bounds__(256) void gemm_bt(const ushort* __restrict__ A,
                                               const ushort* __restrict__ Bt,
                                               const float* __restrict__ bias,
                                               float* __restrict__ Cout,
                                               int Nsz, int Ksz) {
    __shared__ ushort As[2][128 * 32];
    __shared__ ushort Bs[2][128 * 32];
    const int tid = threadIdx.x;
    const int lane = tid & 63, wid = tid >> 6;
    const int wm = wid >> 1, wn = wid & 1;
    const int lin = blockIdx.x + blockIdx.y * 32;
    const int swz = (lin & 7) * 32 + (lin >> 3);
    const int bm = (swz & 31) * 128, bn = (swz >> 5) * 128;
    const int g = lane >> 4, r16 = lane & 15;

    f32x4 acc[4][4] = {};

    const int srow = tid >> 2;
    const int sc = (tid & 3) ^ (srow & 3);
    const ushort* ga0 = A + (size_t)(bm + srow) * Ksz + sc * 8;
    const ushort* ga1 = A + (size_t)(bm + 64 + srow) * Ksz + sc * 8;
    const ushort* gb0 = Bt + (size_t)(bn + srow) * Ksz + sc * 8;
    const ushort* gb1 = Bt + (size_t)(bn + 64 + srow) * Ksz + sc * 8;
    const int lofs = wid << 9;

#define GSTAGE(bufi, k_)  do {                          \
        gll16(ga0 + (k_), &As[bufi][lofs]);             \
        gll16(ga1 + (k_), &As[bufi][2048 + lofs]);      \
        gll16(gb0 + (k_), &Bs[bufi][lofs]);             \
        gll16(gb1 + (k_), &Bs[bufi][2048 + lofs]);      \
    } while (0)

    GSTAGE(0, 0);
    int cur = 0;

    for (int k0 = 0; k0 < Ksz; k0 += 32) {
        __syncthreads();
        if (k0 + 32 < Ksz) GSTAGE(cur ^ 1, k0 + 32);
        const ushort* Asb = As[cur];
        const ushort* Bsb = Bs[cur];
        bf16x8 af[4], bfr[4];
#pragma unroll
        for (int mt = 0; mt < 4; mt++) {
            int row = wm * 64 + mt * 16 + r16;
            af[mt] = *(const bf16x8*)(Asb + row * 32 + ((g ^ (row & 3)) * 8));
        }
#pragma unroll
        for (int nt = 0; nt < 4; nt++) {
            int row = wn * 64 + nt * 16 + r16;
            bfr[nt] = *(const bf16x8*)(Bsb + row * 32 + ((g ^ (row & 3)) * 8));
        }
#pragma unroll
        for (int mt = 0; mt < 4; mt++)
#pragma unroll
            for (int nt = 0; nt < 4; nt++)
                acc[mt][nt] = __builtin_amdgcn_mfma_f32_16x16x32_bf16(af[mt], bfr[nt], acc[mt][nt], 0, 0, 0);
        cur ^= 1;
    }
#undef GSTAGE

#pragma unroll
    for (int nt = 0; nt < 4; nt++) {
        int col = bn + wn * 64 + nt * 16 + r16;
        float bv = bias[col];
#pragma unroll
        for (int mt = 0; mt < 4; mt++) {
            int row0 = bm + wm * 64 + mt * 16 + g * 4;
            f32x4 c = acc[mt][nt];
#pragma unroll
            for (int i = 0; i < 4; i++)
                Cout[(size_t)(row0 + i) * Nsz + col] = c[i] + bv;
        }
    }
}

// ---------------- flash attention: 1 wave/block, wave-private double-buffered LDS, NO barriers ----------------
// Per tile: {s_waitcnt vmcnt(0) [tile t resident]; STAGE(t+1); QKT(t); SOFTPV(t)}.
// All LDS producer/consumer pairs are same-wave (gll16 -> own vmcnt wait -> own ds_read);
// zero cross-wave synchronization. 32768 B LDS -> 5 blocks/CU.
__global__ __launch_bounds__(64) void attn(const ushort* __restrict__ Qp,
                                           const ushort* __restrict__ Kp,
                                           const ushort* __restrict__ Vp,
                                           ushort* __restrict__ Ctx) {
    __shared__ ushort Ks[2][4096];
    __shared__ ushort Vs[2][4096];
    const int lane = threadIdx.x;
    const int lin = blockIdx.x + blockIdx.y * 64;
    const int swz = (lin & 7) * 256 + (lin >> 3);   // XCD-chunked bijective (2048 = 8*256)
    const int bxl = swz & 63, bh = swz >> 6;
    const int b = bh >> 4, h = bh & 15;
    const int l31 = lane & 31, hi = lane >> 5, sw7 = l31 & 7;
    const bool lo = (hi == 0);
    const int qrow = bxl * 32;

    const ushort* Qr = Qp + (size_t)(b * Seq + qrow + l31) * 1024 + h * 64;
    bf16x8 qf[4];
#pragma unroll
    for (int ks = 0; ks < 4; ks++)
        qf[ks] = *(const bf16x8*)(Qr + ks * 16 + hi * 8);

    const ushort* KpB = Kp + (size_t)bh * Seq * 64;
    const ushort* VpB = Vp + (size_t)bh * Seq * 64;

    f32x16 M8;
#pragma unroll
    for (int r = 0; r < 16; r++) M8[r] = -8.f;   // loop-invariant exp2-bias C-init

#define STAGE(slot, tile_)  do {                                        \
        const ushort* ks_ = KpB + (size_t)(tile_) * 4096 + lane * 8;    \
        const ushort* vs_ = VpB + (size_t)(tile_) * 4096 + lane * 8;    \
        _Pragma("unroll")                                               \
        for (int j = 0; j < 8; j++) {                                   \
            gll16(ks_ + j * 512, &Ks[slot][j * 512]);                   \
            gll16(vs_ + j * 512, &Vs[slot][j * 512]);                   \
        }                                                               \
    } while (0)

    f32x16 c0 = {}, c1 = {};
    float l_run = 0.f;

    auto QKT = [&](const ushort* Kt, f32x16& d0, f32x16& d1) {
        __builtin_amdgcn_s_setprio(1);
        {
            int ch = ((hi) ^ sw7) << 3;   // ks = 0: C-in = M8
            bf16x8 k0 = *(const bf16x8*)(Kt + l31 * 64 + ch);
            bf16x8 k1 = *(const bf16x8*)(Kt + (32 + l31) * 64 + ch);
            d0 = __builtin_amdgcn_mfma_f32_32x32x16_bf16(k0, qf[0], M8, 0, 0, 0);
            d1 = __builtin_amdgcn_mfma_f32_32x32x16_bf16(k1, qf[0], M8, 0, 0, 0);
        }
#pragma unroll
        for (int ks = 1; ks < 4; ks++) {
            int ch = ((ks * 2 + hi) ^ sw7) << 3;
            bf16x8 k0 = *(const bf16x8*)(Kt + l31 * 64 + ch);
            bf16x8 k1 = *(const bf16x8*)(Kt + (32 + l31) * 64 + ch);
            d0 = __builtin_amdgcn_mfma_f32_32x32x16_bf16(k0, qf[ks], d0, 0, 0, 0);
            d1 = __builtin_amdgcn_mfma_f32_32x32x16_bf16(k1, qf[ks], d1, 0, 0, 0);
        }
        __builtin_amdgcn_s_setprio(0);
    };
    auto SOFTPV = [&](const f32x16& s0, const f32x16& s1, const ushort* Vt) {
        float p0[16], p1[16];
        float ls = 0.f;
#pragma unroll
        for (int r = 0; r < 16; r++) {
            p0[r] = EXP2(s0[r]);
            p1[r] = EXP2(s1[r]);
            ls += p0[r] + p1[r];
        }
        l_run += ls;
        bf16x8 pa[4];
#pragma unroll
        for (int sl = 0; sl < 4; sl++) {
            const float* pp = (sl < 2) ? p0 : p1;
            int rb = (sl & 1) * 8;
            uint x  = cvt_pk_bf16(pp[rb + 0], pp[rb + 1]);
            uint x2 = cvt_pk_bf16(pp[rb + 2], pp[rb + 3]);
            uint y  = cvt_pk_bf16(pp[rb + 4], pp[rb + 5]);
            uint y2 = cvt_pk_bf16(pp[rb + 6], pp[rb + 7]);
            asm("v_permlane32_swap_b32 %0, %1" : "+v"(x),  "+v"(y));
            asm("v_permlane32_swap_b32 %0, %1" : "+v"(x2), "+v"(y2));
            union { uint u[4]; bf16x8 v; } fr;
            fr.u[0] = x;
            fr.u[1] = x2;
            fr.u[2] = y;
            fr.u[3] = y2;
            pa[sl] = fr.v;
        }
        __builtin_amdgcn_s_setprio(1);
#pragma unroll
        for (int sl = 0; sl < 4; sl++) {
            int ch = ((sl * 2 + hi) ^ sw7) << 3;
            bf16x8 vf0 = *(const bf16x8*)(Vt + l31 * 64 + ch);
            bf16x8 vf1 = *(const bf16x8*)(Vt + (32 + l31) * 64 + ch);
            c0 = __builtin_amdgcn_mfma_f32_32x32x16_bf16(pa[sl], vf0, c0, 0, 0, 0);
            c1 = __builtin_amdgcn_mfma_f32_32x32x16_bf16(pa[sl], vf1, c1, 0, 0, 0);
        }
        __builtin_amdgcn_s_setprio(0);
    };

    f32x16 sA0, sA1;
    STAGE(0, 0);
    for (int t = 0; t < 32; ++t) {
        const int cur = t & 1;
        __builtin_amdgcn_sched_barrier(0);
        asm volatile("s_waitcnt vmcnt(0)" ::: "memory");   // tile t resident (wave-own loads)
        __builtin_amdgcn_sched_barrier(0);
        if (t + 1 < 32) STAGE(cur ^ 1, t + 1);             // overlaps with compute below
        QKT(Ks[cur], sA0, sA1);
        SOFTPV(sA0, sA1, Vs[cur]);
    }
#undef STAGE

    // final normalize: 1/l per q via tiny LDS table overlaid on Ks (all Ks reads complete)
    float lt = l_run + __shfl_xor(l_run, 32);
    float* RlP = (float*)&Ks[0][0];
    if (lo) RlP[l31] = 1.f / lt;
    __builtin_amdgcn_s_waitcnt(0);
    float rlv[16];
#pragma unroll
    for (int r = 0; r < 16; r++)
        rlv[r] = RlP[(r & 3) + 8 * (r >> 2) + 4 * hi];

    const int rowbase = b * Seq + qrow;
#pragma unroll
    for (int r = 0; r < 16; r++) {
        int q = (r & 3) + 8 * (r >> 2) + 4 * hi;
        int row = rowbase + q;
        Ctx[(size_t)row * Dim + h * 64 + l31]      = f2bf(c0[r] * rlv[r]);
        Ctx[(size_t)row * Dim + h * 64 + 32 + l31] = f2bf(c1[r] * rlv[r]);
    }
}

extern "C" void kernel_launch(void* const* d_in, const int* in_sizes, int n_in,
                              void* d_out, int out_size, void* d_ws, size_t ws_size,
                              hipStream_t stream) {
    const float* X  = (const float*)d_in[0];
    const float* Wq = (const float*)d_in[1];
    const float* bq = (const float*)d_in[2];
    const float* Wk = (const float*)d_in[3];
    const float* bk = (const float*)d_in[4];
    const float* Wv = (const float*)d_in[5];
    const float* bv = (const float*)d_in[6];
    const float* Wo = (const float*)d_in[7];
    const float* bo = (const float*)d_in[8];

    char* ws = (char*)d_ws;
    ushort* Xb    = (ushort*)(ws);                      //  8 MB (plain)
    ushort* Wtqkv = (ushort*)(ws + 8388608);            //  6 MB (plain)
    ushort* Wto   = (ushort*)(ws + 14680064);           //  2 MB (plain)
    float*  bqkv  = (float*)(ws + 16777216);            // 16 KB
    ushort* Qp    = (ushort*)(ws + 16793600);           //  8 MB
    ushort* Kp    = (ushort*)(ws + 25182208);           //  8 MB
    ushort* Vp    = (ushort*)(ws + 33570816);           //  8 MB
    ushort* Ctxb  = (ushort*)(ws + 41959424);           //  8 MB (plain)

    prep<<<5132, 256, 0, stream>>>(X, Wq, Wk, Wv, Wo, bq, bk, bv, Xb, Wtqkv, Wto, bqkv);
    gemm_qkv<<<dim3(16, 12), 512, 0, stream>>>(Xb, Wtqkv, bqkv, Qp, Kp, Vp);
    attn<<<dim3(64, 32), 64, 0, stream>>>(Qp, Kp, Vp, Ctxb);
    gemm_bt<<<dim3(32, 8), 256, 0, stream>>>(Ctxb, Wto, bo, (float*)d_out, Dim, Dim);
}

// Round 19
// 119.379 us; speedup vs baseline: 1.3752x; 1.3752x over previous
//
#include <hip/hip_runtime.h>
#include <hip/hip_bf16.h>
#include <cstdint>

constexpr int Bsz = 2, Seq = 2048, Dim = 1024, NH = 16, HDim = 64;
constexpr int Mtok = Bsz * Seq;           // 4096
constexpr int NQKV = 3 * Dim;             // 3072
constexpr float QSCALE = 0.125f * 1.4426950408889634f;  // 1/sqrt(64) * log2(e)

typedef __attribute__((ext_vector_type(4))) float f32x4;
typedef __attribute__((ext_vector_type(16))) float f32x16;
typedef __attribute__((ext_vector_type(8))) short bf16x8;

#if __has_builtin(__builtin_amdgcn_exp2f)
#define EXP2(x) __builtin_amdgcn_exp2f(x)
#else
#define EXP2(x) exp2f(x)
#endif

__device__ __forceinline__ ushort f2bf(float f) {
    union { float f; uint32_t u; } v; v.f = f;
    uint32_t u = v.u;
    uint32_t r = (u + 0x7fffu + ((u >> 16) & 1u)) >> 16;
    return (ushort)r;
}

__device__ __forceinline__ uint cvt_pk_bf16(float lo, float hi) {
    uint r;
    asm("v_cvt_pk_bf16_f32 %0, %1, %2" : "=v"(r) : "v"(lo), "v"(hi));
    return r;
}

__device__ __forceinline__ void gll16(const ushort* g, ushort* l) {
    __builtin_amdgcn_global_load_lds(
        (const __attribute__((address_space(1))) void*)g,
        (__attribute__((address_space(3))) void*)l, 16, 0, 0);
}

// ---------------- fused prep: X->bf16 | 4x W transpose | bias concat ----------------
__global__ __launch_bounds__(256) void prep(const float* __restrict__ X,
                                            const float* __restrict__ Wq, const float* __restrict__ Wk,
                                            const float* __restrict__ Wv, const float* __restrict__ Wo,
                                            const float* __restrict__ bq, const float* __restrict__ bk,
                                            const float* __restrict__ bv,
                                            ushort* __restrict__ Xb, ushort* __restrict__ Wtqkv,
                                            ushort* __restrict__ Wto, float* __restrict__ bqkv) {
    __shared__ float tile[32][33];
    const int bid = blockIdx.x, tid = threadIdx.x;
    if (bid < 1024) {
        int i = bid * 256 + tid;
        const float4* p = (const float4*)X + (size_t)i * 4;
        float4 a = p[0], b = p[1], c2 = p[2], d = p[3];
        uint4 o0, o1;
        o0.x = (uint)f2bf(a.x) | ((uint)f2bf(a.y) << 16);
        o0.y = (uint)f2bf(a.z) | ((uint)f2bf(a.w) << 16);
        o0.z = (uint)f2bf(b.x) | ((uint)f2bf(b.y) << 16);
        o0.w = (uint)f2bf(b.z) | ((uint)f2bf(b.w) << 16);
        o1.x = (uint)f2bf(c2.x) | ((uint)f2bf(c2.y) << 16);
        o1.y = (uint)f2bf(c2.z) | ((uint)f2bf(c2.w) << 16);
        o1.z = (uint)f2bf(d.x) | ((uint)f2bf(d.y) << 16);
        o1.w = (uint)f2bf(d.z) | ((uint)f2bf(d.w) << 16);
        uint4* dst = (uint4*)Xb + (size_t)i * 2;
        dst[0] = o0;
        dst[1] = o1;
    } else if (bid < 5120) {
        int zb = bid - 1024;
        int z = zb >> 10, r2 = zb & 1023;
        int bx = (r2 & 31) * 32, by = (r2 >> 5) * 32;
        const float* src = (z == 0) ? Wq : (z == 1) ? Wk : (z == 2) ? Wv : Wo;
        ushort* dst = (z == 3) ? Wto : Wtqkv + (size_t)z * 1024 * 1024;
        float scale = (z == 0) ? QSCALE : 1.f;
        int tx = tid & 31, ty = tid >> 5;   // 32 x 8
#pragma unroll
        for (int j = 0; j < 32; j += 8)
            tile[ty + j][tx] = src[(size_t)(by + ty + j) * Dim + bx + tx];
        __syncthreads();
#pragma unroll
        for (int j = 0; j < 32; j += 8) {
            int n = bx + ty + j;
            dst[(size_t)n * Dim + by + tx] = f2bf(tile[tx][ty + j] * scale);
        }
    } else {
        int i = (bid - 5120) * 256 + tid;
        float v = (i < 1024) ? bq[i] * QSCALE : (i < 2048 ? bk[i - 1024] : bv[i - 2048]);
        bqkv[i] = v;
    }
}

// ---------------- QKV GEMM: 256x256 tile, BK=64, 8 waves, counted-vmcnt phase schedule ----------------
// XCD-chunked bijective swizzle (192 blocks, 24/XCD).
__global__ __launch_bounds__(512, 2) void gemm_qkv(const ushort* __restrict__ A,
                                                   const ushort* __restrict__ Bt,
                                                   const float* __restrict__ bias,
                                                   ushort* __restrict__ Qp,
                                                   ushort* __restrict__ Kp,
                                                   ushort* __restrict__ Vp) {
    __shared__ ushort Al[2][2][8192];
    __shared__ ushort Bl[2][2][8192];
    const int tid = threadIdx.x;
    const int lane = tid & 63, wid = tid >> 6;
    const int wm = wid >> 2, wn = wid & 3;
    const int g = lane >> 4, r16 = lane & 15;
    const int sw = r16 & 7;
    const int lin = blockIdx.x + blockIdx.y * 16;
    const int swz = (lin & 7) * 24 + (lin >> 3);
    const int by = swz >> 4;
    const int bm = (swz & 15) * 256, bn = by * 256;
    const int srow = tid >> 3;
    const int gch = (tid & 7) ^ (srow & 7);
    const int wofs = wid * 512;

    const ushort* gAb = A  + (size_t)(bm + srow) * 1024 + gch * 8;
    const ushort* gBb = Bt + (size_t)(bn + srow) * 1024 + gch * 8;

#define STAGE_A(buf, h, t) do {                                          \
        const ushort* s_ = gAb + (size_t)(h) * 131072 + (t) * 64;        \
        gll16(s_,         &Al[buf][h][wofs]);                            \
        gll16(s_ + 65536, &Al[buf][h][4096 + wofs]);                     \
    } while (0)
#define STAGE_B(buf, h, t) do {                                          \
        const ushort* s_ = gBb + (size_t)(h) * 131072 + (t) * 64;        \
        gll16(s_,         &Bl[buf][h][wofs]);                            \
        gll16(s_ + 65536, &Bl[buf][h][4096 + wofs]);                     \
    } while (0)
#define LDA(buf, mi, ks) (*(const bf16x8*)&Al[buf][wm][((mi)*16 + r16) * 64 + ((((ks)*4 + g) ^ sw) * 8)])
#define LDB(buf, ni, ks) (*(const bf16x8*)&Bl[buf][wn >> 1][((wn & 1) * 64 + (ni)*16 + r16) * 64 + ((((ks)*4 + g) ^ sw) * 8)])

    f32x4 acc[8][4] = {};
    bf16x8 a0[4][2], a1[4][2], bA[2][2], bB[2][2];

    STAGE_A(0, 0, 0); STAGE_A(0, 1, 0); STAGE_B(0, 0, 0); STAGE_B(0, 1, 0);
    STAGE_A(1, 0, 1); STAGE_A(1, 1, 1); STAGE_B(1, 0, 1); STAGE_B(1, 1, 1);
    asm volatile("s_waitcnt vmcnt(8)" ::: "memory");
    __builtin_amdgcn_s_barrier();
    __builtin_amdgcn_sched_barrier(0);

#pragma unroll 2
    for (int t = 0; t < 16; ++t) {
        const int buf = t & 1;
#pragma unroll
        for (int mi = 0; mi < 4; mi++) { a0[mi][0] = LDA(buf, mi, 0); a0[mi][1] = LDA(buf, mi, 1); }
#pragma unroll
        for (int ni = 0; ni < 2; ni++) { bA[ni][0] = LDB(buf, ni, 0); bA[ni][1] = LDB(buf, ni, 1); }
        __builtin_amdgcn_s_setprio(1);
#pragma unroll
        for (int mi = 0; mi < 4; mi++)
#pragma unroll
            for (int ni = 0; ni < 2; ni++)
#pragma unroll
                for (int ks = 0; ks < 2; ks++)
                    acc[mi][ni] = __builtin_amdgcn_mfma_f32_16x16x32_bf16(a0[mi][ks], bA[ni][ks], acc[mi][ni], 0, 0, 0);
        __builtin_amdgcn_s_setprio(0);
#pragma unroll
        for (int ni = 0; ni < 2; ni++) { bB[ni][0] = LDB(buf, 2 + ni, 0); bB[ni][1] = LDB(buf, 2 + ni, 1); }
        __builtin_amdgcn_s_setprio(1);
#pragma unroll
        for (int mi = 0; mi < 4; mi++)
#pragma unroll
            for (int ni = 0; ni < 2; ni++)
#pragma unroll
                for (int ks = 0; ks < 2; ks++)
                    acc[mi][2 + ni] = __builtin_amdgcn_mfma_f32_16x16x32_bf16(a0[mi][ks], bB[ni][ks], acc[mi][2 + ni], 0, 0, 0);
        __builtin_amdgcn_s_setprio(0);
        __builtin_amdgcn_s_barrier();
        __builtin_amdgcn_sched_barrier(0);
#pragma unroll
        for (int mi = 0; mi < 4; mi++) { a1[mi][0] = LDA(buf, 4 + mi, 0); a1[mi][1] = LDA(buf, 4 + mi, 1); }
        if (t + 2 < 16) { STAGE_B(buf, 0, t + 2); STAGE_B(buf, 1, t + 2); }
        __builtin_amdgcn_s_setprio(1);
#pragma unroll
        for (int mi = 0; mi < 4; mi++)
#pragma unroll
            for (int ni = 0; ni < 2; ni++)
#pragma unroll
                for (int ks = 0; ks < 2; ks++)
                    acc[4 + mi][2 + ni] = __builtin_amdgcn_mfma_f32_16x16x32_bf16(a1[mi][ks], bB[ni][ks], acc[4 + mi][2 + ni], 0, 0, 0);
        __builtin_amdgcn_s_setprio(0);
        __builtin_amdgcn_s_barrier();
        __builtin_amdgcn_sched_barrier(0);
        if (t + 2 < 16) { STAGE_A(buf, 0, t + 2); STAGE_A(buf, 1, t + 2); }
        __builtin_amdgcn_s_setprio(1);
#pragma unroll
        for (int mi = 0; mi < 4; mi++)
#pragma unroll
            for (int ni = 0; ni < 2; ni++)
#pragma unroll
                for (int ks = 0; ks < 2; ks++)
                    acc[4 + mi][ni] = __builtin_amdgcn_mfma_f32_16x16x32_bf16(a1[mi][ks], bA[ni][ks], acc[4 + mi][ni], 0, 0, 0);
        __builtin_amdgcn_s_setprio(0);
        if (t + 2 < 16) asm volatile("s_waitcnt vmcnt(8)" ::: "memory");
        else            asm volatile("s_waitcnt vmcnt(0)" ::: "memory");
        __builtin_amdgcn_s_barrier();
        __builtin_amdgcn_sched_barrier(0);
    }
#undef STAGE_A
#undef STAGE_B
#undef LDA
#undef LDB

#pragma unroll
    for (int ni = 0; ni < 4; ni++) {
        const int col = bn + wn * 64 + ni * 16 + r16;
        const float bv = bias[col];
        if (by < 4) {
#pragma unroll
            for (int mi = 0; mi < 8; mi++) {
                int row0 = bm + wm * 128 + mi * 16 + g * 4;
                f32x4 c = acc[mi][ni];
#pragma unroll
                for (int i = 0; i < 4; i++)
                    Qp[(size_t)(row0 + i) * 1024 + col] = f2bf(c[i] + bv);
            }
        } else if (by < 8) {
            int h = ((bn - 1024) >> 6) + wn;
            int d = ni * 16 + r16;
#pragma unroll
            for (int mi = 0; mi < 8; mi++) {
                int row0 = bm + wm * 128 + mi * 16 + g * 4;
                f32x4 c = acc[mi][ni];
#pragma unroll
                for (int i = 0; i < 4; i++) {
                    int row = row0 + i;
                    int b = row >> 11, s = row & 2047;
                    size_t idx = ((size_t)(b * 16 + h) * 2048 + s) * 64
                               + (((d >> 3) ^ (s & 7)) << 3) + (d & 7);
                    Kp[idx] = f2bf(c[i] + bv);
                }
            }
        } else {
            int h = ((bn - 2048) >> 6) + wn;
            int dv = ni * 16 + r16;
#pragma unroll
            for (int mi = 0; mi < 8; mi++) {
                int row0 = bm + wm * 128 + mi * 16 + g * 4;
                f32x4 c = acc[mi][ni];
                int b = row0 >> 11, s = row0 & 2047;
                int s0 = s & ~63, si = s & 63;
                uint2 pk;
                pk.x = cvt_pk_bf16(c[0] + bv, c[1] + bv);
                pk.y = cvt_pk_bf16(c[2] + bv, c[3] + bv);
                size_t idx = ((size_t)(b * 16 + h) * 2048 + s0) * 64 + dv * 64
                           + (((si >> 3) ^ (dv & 7)) << 3) + (si & 7);
                *(uint2*)(Vp + idx) = pk;
            }
        }
    }
}

// ---------------- out-proj GEMM (XCD swizzle: 256 blocks, 32/XCD) ----------------
__global__ __launch_bounds__(256) void gemm_bt(const ushort* __restrict__ A,
                                               const ushort* __restrict__ Bt,
                                               const float* __restrict__ bias,
                                               float* __restrict__ Cout,
                                               int Nsz, int Ksz) {
    __shared__ ushort As[2][128 * 32];
    __shared__ ushort Bs[2][128 * 32];
    const int tid = threadIdx.x;
    const int lane = tid & 63, wid = tid >> 6;
    const int wm = wid >> 1, wn = wid & 1;
    const int lin = blockIdx.x + blockIdx.y * 32;
    const int swz = (lin & 7) * 32 + (lin >> 3);
    const int bm = (swz & 31) * 128, bn = (swz >> 5) * 128;
    const int g = lane >> 4, r16 = lane & 15;

    f32x4 acc[4][4] = {};

    const int srow = tid >> 2;
    const int sc = (tid & 3) ^ (srow & 3);
    const ushort* ga0 = A + (size_t)(bm + srow) * Ksz + sc * 8;
    const ushort* ga1 = A + (size_t)(bm + 64 + srow) * Ksz + sc * 8;
    const ushort* gb0 = Bt + (size_t)(bn + srow) * Ksz + sc * 8;
    const ushort* gb1 = Bt + (size_t)(bn + 64 + srow) * Ksz + sc * 8;
    const int lofs = wid << 9;

#define GSTAGE(bufi, k_)  do {                          \
        gll16(ga0 + (k_), &As[bufi][lofs]);             \
        gll16(ga1 + (k_), &As[bufi][2048 + lofs]);      \
        gll16(gb0 + (k_), &Bs[bufi][lofs]);             \
        gll16(gb1 + (k_), &Bs[bufi][2048 + lofs]);      \
    } while (0)

    GSTAGE(0, 0);
    int cur = 0;

    for (int k0 = 0; k0 < Ksz; k0 += 32) {
        __syncthreads();
        if (k0 + 32 < Ksz) GSTAGE(cur ^ 1, k0 + 32);
        const ushort* Asb = As[cur];
        const ushort* Bsb = Bs[cur];
        bf16x8 af[4], bfr[4];
#pragma unroll
        for (int mt = 0; mt < 4; mt++) {
            int row = wm * 64 + mt * 16 + r16;
            af[mt] = *(const bf16x8*)(Asb + row * 32 + ((g ^ (row & 3)) * 8));
        }
#pragma unroll
        for (int nt = 0; nt < 4; nt++) {
            int row = wn * 64 + nt * 16 + r16;
            bfr[nt] = *(const bf16x8*)(Bsb + row * 32 + ((g ^ (row & 3)) * 8));
        }
#pragma unroll
        for (int mt = 0; mt < 4; mt++)
#pragma unroll
            for (int nt = 0; nt < 4; nt++)
                acc[mt][nt] = __builtin_amdgcn_mfma_f32_16x16x32_bf16(af[mt], bfr[nt], acc[mt][nt], 0, 0, 0);
        cur ^= 1;
    }
#undef GSTAGE

#pragma unroll
    for (int nt = 0; nt < 4; nt++) {
        int col = bn + wn * 64 + nt * 16 + r16;
        float bv = bias[col];
#pragma unroll
        for (int mt = 0; mt < 4; mt++) {
            int row0 = bm + wm * 64 + mt * 16 + g * 4;
            f32x4 c = acc[mt][nt];
#pragma unroll
            for (int i = 0; i < 4; i++)
                Cout[(size_t)(row0 + i) * Nsz + col] = c[i] + bv;
        }
    }
}

// ---------------- flash attention: r12/r15/r17-proven 3-slot ring + QK-one-ahead pipeline ----------------
// (1-wave-private variant reverted: r18 showed occupancy COLLAPSE — single-wave blocks
//  under-fill CUs and expose per-tile staging latency serially.)
__global__ __launch_bounds__(256) void attn(const ushort* __restrict__ Qp,
                                            const ushort* __restrict__ Kp,
                                            const ushort* __restrict__ Vp,
                                            ushort* __restrict__ Ctx) {
    __shared__ ushort Ks[3][4096];
    __shared__ ushort Vs[3][4096];
    __shared__ float Rl[4][32];
    const int tid = threadIdx.x, lane = tid & 63, w = tid >> 6;
    const int lin = blockIdx.x + blockIdx.y * 16;
    const int swz = (lin & 7) * 64 + (lin >> 3);
    const int bxl = swz & 15, bh = swz >> 4;
    const int b = bh >> 4, h = bh & 15;
    const int l31 = lane & 31, hi = lane >> 5, sw7 = l31 & 7;
    const bool lo = (hi == 0);
    const int qrow = bxl * 128 + w * 32;

    const ushort* Qr = Qp + (size_t)(b * Seq + qrow + l31) * 1024 + h * 64;
    bf16x8 qf[4];
#pragma unroll
    for (int ks = 0; ks < 4; ks++)
        qf[ks] = *(const bf16x8*)(Qr + ks * 16 + hi * 8);

    const ushort* KpB = Kp + (size_t)bh * Seq * 64;
    const ushort* VpB = Vp + (size_t)bh * Seq * 64;
    const int wb = w * 512;

    f32x16 M8;
#pragma unroll
    for (int r = 0; r < 16; r++) M8[r] = -8.f;   // loop-invariant exp2-bias C-init

#define STAGE(slot, kv0_)  do {                                        \
        const ushort* ks_ = KpB + (size_t)(kv0_) * 64 + tid * 8;       \
        const ushort* vs_ = VpB + (size_t)(kv0_) * 64 + tid * 8;       \
        gll16(ks_,        &Ks[slot][wb]);                              \
        gll16(ks_ + 2048, &Ks[slot][2048 + wb]);                       \
        gll16(vs_,        &Vs[slot][wb]);                              \
        gll16(vs_ + 2048, &Vs[slot][2048 + wb]);                       \
    } while (0)

    f32x16 c0 = {}, c1 = {};
    float l_run = 0.f;

    auto QKT = [&](const ushort* Kt, f32x16& d0, f32x16& d1) {
        __builtin_amdgcn_s_setprio(1);
        {
            int ch = ((hi) ^ sw7) << 3;   // ks = 0: C-in = M8 (no per-tile init)
            bf16x8 k0 = *(const bf16x8*)(Kt + l31 * 64 + ch);
            bf16x8 k1 = *(const bf16x8*)(Kt + (32 + l31) * 64 + ch);
            d0 = __builtin_amdgcn_mfma_f32_32x32x16_bf16(k0, qf[0], M8, 0, 0, 0);
            d1 = __builtin_amdgcn_mfma_f32_32x32x16_bf16(k1, qf[0], M8, 0, 0, 0);
        }
#pragma unroll
        for (int ks = 1; ks < 4; ks++) {
            int ch = ((ks * 2 + hi) ^ sw7) << 3;
            bf16x8 k0 = *(const bf16x8*)(Kt + l31 * 64 + ch);
            bf16x8 k1 = *(const bf16x8*)(Kt + (32 + l31) * 64 + ch);
            d0 = __builtin_amdgcn_mfma_f32_32x32x16_bf16(k0, qf[ks], d0, 0, 0, 0);
            d1 = __builtin_amdgcn_mfma_f32_32x32x16_bf16(k1, qf[ks], d1, 0, 0, 0);
        }
        __builtin_amdgcn_s_setprio(0);
    };
    auto SOFTPV = [&](const f32x16& s0, const f32x16& s1, const ushort* Vt) {
        float p0[16], p1[16];
        float ls = 0.f;
#pragma unroll
        for (int r = 0; r < 16; r++) {
            p0[r] = EXP2(s0[r]);
            p1[r] = EXP2(s1[r]);
            ls += p0[r] + p1[r];
        }
        l_run += ls;
        bf16x8 pa[4];
#pragma unroll
        for (int sl = 0; sl < 4; sl++) {
            const float* pp = (sl < 2) ? p0 : p1;
            int rb = (sl & 1) * 8;
            uint x  = cvt_pk_bf16(pp[rb + 0], pp[rb + 1]);
            uint x2 = cvt_pk_bf16(pp[rb + 2], pp[rb + 3]);
            uint y  = cvt_pk_bf16(pp[rb + 4], pp[rb + 5]);
            uint y2 = cvt_pk_bf16(pp[rb + 6], pp[rb + 7]);
            asm("v_permlane32_swap_b32 %0, %1" : "+v"(x),  "+v"(y));
            asm("v_permlane32_swap_b32 %0, %1" : "+v"(x2), "+v"(y2));
            union { uint u[4]; bf16x8 v; } fr;
            fr.u[0] = x;
            fr.u[1] = x2;
            fr.u[2] = y;
            fr.u[3] = y2;
            pa[sl] = fr.v;
        }
        __builtin_amdgcn_s_setprio(1);
#pragma unroll
        for (int sl = 0; sl < 4; sl++) {
            int ch = ((sl * 2 + hi) ^ sw7) << 3;
            bf16x8 vf0 = *(const bf16x8*)(Vt + l31 * 64 + ch);
            bf16x8 vf1 = *(const bf16x8*)(Vt + (32 + l31) * 64 + ch);
            c0 = __builtin_amdgcn_mfma_f32_32x32x16_bf16(pa[sl], vf0, c0, 0, 0, 0);
            c1 = __builtin_amdgcn_mfma_f32_32x32x16_bf16(pa[sl], vf1, c1, 0, 0, 0);
        }
        __builtin_amdgcn_s_setprio(0);
    };

    // prologue: tiles 0,1 staged; QK(0)
    STAGE(0, 0);
    STAGE(1, 64);
    __syncthreads();
    f32x16 sA0, sA1, sB0, sB1;
    QKT(Ks[0], sA0, sA1);

    int sa = 0, sb = 1, scs = 2;
    for (int t = 0; t < 32; t += 2) {
        // ---- half A: tile t (scores sA); QK(t+1) ahead
        __syncthreads();                          // stage(t+1) resident; slot scs's old reads done
        if (t + 2 < 32) STAGE(scs, (t + 2) * 64);
        QKT(Ks[sb], sB0, sB1);                    // tile t+1
        SOFTPV(sA0, sA1, Vs[sa]);                 // tile t
        // ---- half B: tile t+1 (scores sB); QK(t+2) ahead
        __syncthreads();
        if (t + 3 < 32) STAGE(sa, (t + 3) * 64);
        if (t + 2 < 32) QKT(Ks[scs], sA0, sA1);   // tile t+2
        SOFTPV(sB0, sB1, Vs[sb]);                 // tile t+1
        int tmp = sa; sa = scs; scs = sb; sb = tmp;
    }
#undef STAGE

    float lt = l_run + __shfl_xor(l_run, 32);
    if (lo) Rl[w][l31] = 1.f / lt;
    __builtin_amdgcn_s_waitcnt(0);
    float rlv[16];
#pragma unroll
    for (int r = 0; r < 16; r++)
        rlv[r] = Rl[w][(r & 3) + 8 * (r >> 2) + 4 * hi];

    const int rowbase = b * Seq + qrow;
#pragma unroll
    for (int r = 0; r < 16; r++) {
        int q = (r & 3) + 8 * (r >> 2) + 4 * hi;
        int row = rowbase + q;
        Ctx[(size_t)row * Dim + h * 64 + l31]      = f2bf(c0[r] * rlv[r]);
        Ctx[(size_t)row * Dim + h * 64 + 32 + l31] = f2bf(c1[r] * rlv[r]);
    }
}

extern "C" void kernel_launch(void* const* d_in, const int* in_sizes, int n_in,
                              void* d_out, int out_size, void* d_ws, size_t ws_size,
                              hipStream_t stream) {
    const float* X  = (const float*)d_in[0];
    const float* Wq = (const float*)d_in[1];
    const float* bq = (const float*)d_in[2];
    const float* Wk = (const float*)d_in[3];
    const float* bk = (const float*)d_in[4];
    const float* Wv = (const float*)d_in[5];
    const float* bv = (const float*)d_in[6];
    const float* Wo = (const float*)d_in[7];
    const float* bo = (const float*)d_in[8];

    char* ws = (char*)d_ws;
    ushort* Xb    = (ushort*)(ws);                      //  8 MB (plain)
    ushort* Wtqkv = (ushort*)(ws + 8388608);            //  6 MB (plain)
    ushort* Wto   = (ushort*)(ws + 14680064);           //  2 MB (plain)
    float*  bqkv  = (float*)(ws + 16777216);            // 16 KB
    ushort* Qp    = (ushort*)(ws + 16793600);           //  8 MB
    ushort* Kp    = (ushort*)(ws + 25182208);           //  8 MB
    ushort* Vp    = (ushort*)(ws + 33570816);           //  8 MB
    ushort* Ctxb  = (ushort*)(ws + 41959424);           //  8 MB (plain)

    prep<<<5132, 256, 0, stream>>>(X, Wq, Wk, Wv, Wo, bq, bk, bv, Xb, Wtqkv, Wto, bqkv);
    gemm_qkv<<<dim3(16, 12), 512, 0, stream>>>(Xb, Wtqkv, bqkv, Qp, Kp, Vp);
    attn<<<dim3(16, 32), 256, 0, stream>>>(Qp, Kp, Vp, Ctxb);
    gemm_bt<<<dim3(32, 8), 256, 0, stream>>>(Ctxb, Wto, bo, (float*)d_out, Dim, Dim);
}